// Round 1
// baseline (523.883 us; speedup 1.0000x reference)
//
#include <hip/hip_runtime.h>
#include <hip/hip_bf16.h>
#include <math.h>

typedef unsigned short u16;
typedef __attribute__((ext_vector_type(8))) short bf16x8;   // 8 bf16 = 4 VGPRs
typedef __attribute__((ext_vector_type(4))) float f32x4;

// ---------- helpers ----------
__device__ static inline u16 f2bf(float f) {
  unsigned u = __float_as_uint(f);
  u += 0x7fff + ((u >> 16) & 1);          // RNE; inputs are finite normals
  return (u16)(u >> 16);
}

__device__ static inline void gload_lds16(const void* g, void* l) {
  __builtin_amdgcn_global_load_lds(
      (const __attribute__((address_space(1))) unsigned int*)g,
      (__attribute__((address_space(3))) unsigned int*)l, 16, 0, 0);
}

__device__ static inline void store_out(u16* p, float v)   { *p = f2bf(v); }
__device__ static inline void store_out(float* p, float v) { *p = v; }

// ---------- fp32 -> bf16 convert ----------
__global__ void cvt_f32_bf16(const float* __restrict__ src, u16* __restrict__ dst, int n) {
  int stride = gridDim.x * blockDim.x;
  for (int i = blockIdx.x * blockDim.x + threadIdx.x; i * 8 < n; i += stride) {
    const float4* s4 = (const float4*)(src + (size_t)i * 8);
    float4 a = s4[0], b = s4[1];
    u16 t[8] = { f2bf(a.x), f2bf(a.y), f2bf(a.z), f2bf(a.w),
                 f2bf(b.x), f2bf(b.y), f2bf(b.z), f2bf(b.w) };
    *(bf16x8*)(dst + (size_t)i * 8) = *(bf16x8*)t;
  }
}

// ---------- GEMM: C[M][N] = A[M][K] * B[N][K]^T  (m97 structure) ----------
template <typename OutT>
__global__ __launch_bounds__(256, 2)
void gemm_bt(const u16* __restrict__ A, const u16* __restrict__ Bm,
             OutT* __restrict__ C, int M, int N, int K) {
  __shared__ u16 As[128 * 32];
  __shared__ u16 Bs[128 * 32];
  const int tid = threadIdx.x;
  const int lane = tid & 63;
  const int w = tid >> 6, wr = w >> 1, wc = w & 1;
  const int g = lane >> 4, l16 = lane & 15;
  const int row0 = blockIdx.y * 128, col0 = blockIdx.x * 128;
  f32x4 acc[4][4] = {};

  for (int k0 = 0; k0 < K; k0 += 32) {
    __syncthreads();
#pragma unroll
    for (int i = 0; i < 2; ++i) {
      int idx = i * 256 + tid;            // 512 x 16B chunks per operand
      int r = idx >> 2, c = (idx & 3) * 8;
      gload_lds16(A  + (size_t)(row0 + r) * K + k0 + c, As + idx * 8);
      gload_lds16(Bm + (size_t)(col0 + r) * K + k0 + c, Bs + idx * 8);
    }
    __syncthreads();                      // drains vmcnt(0) before barrier
    bf16x8 af[4], bfr[4];
#pragma unroll
    for (int m2 = 0; m2 < 4; ++m2)
      af[m2] = *(const bf16x8*)(As + (wr * 64 + m2 * 16 + l16) * 32 + g * 8);
#pragma unroll
    for (int n2 = 0; n2 < 4; ++n2)
      bfr[n2] = *(const bf16x8*)(Bs + (wc * 64 + n2 * 16 + l16) * 32 + g * 8);
#pragma unroll
    for (int m2 = 0; m2 < 4; ++m2)
#pragma unroll
      for (int n2 = 0; n2 < 4; ++n2)
        acc[m2][n2] = __builtin_amdgcn_mfma_f32_16x16x32_bf16(af[m2], bfr[n2], acc[m2][n2], 0, 0, 0);
  }

#pragma unroll
  for (int m2 = 0; m2 < 4; ++m2)
#pragma unroll
    for (int n2 = 0; n2 < 4; ++n2) {
      int col = col0 + wc * 64 + n2 * 16 + l16;
#pragma unroll
      for (int r = 0; r < 4; ++r) {
        int row = row0 + wr * 64 + m2 * 16 + g * 4 + r;
        store_out(C + (size_t)row * N + col, acc[m2][n2][r]);
      }
    }
}

// ---------- V transpose: QKV V-part [b,s,h*128+d] -> Vt [b,h,d,s] ----------
__global__ __launch_bounds__(256)
void transpose_v(const u16* __restrict__ QKV, u16* __restrict__ Vt) {
  __shared__ u16 t[64][72];
  const int tid = threadIdx.x;
  const int b = blockIdx.y >> 5;
  const int s0 = (blockIdx.y & 31) * 64;
  const int hd0 = blockIdx.x * 64;
  const int lr = tid >> 2, lc = (tid & 3) * 16;
  const u16* src = QKV + ((size_t)(b * 2048 + s0 + lr) * 6144 + 4096 + hd0 + lc);
  *(bf16x8*)&t[lr][lc]     = *(const bf16x8*)src;
  *(bf16x8*)&t[lr][lc + 8] = *(const bf16x8*)(src + 8);
  __syncthreads();
  u16 tmp[16];
#pragma unroll
  for (int j = 0; j < 16; ++j) tmp[j] = t[lc + j][lr];
  u16* dst = Vt + ((size_t)(b * 2048 + hd0 + lr) * 2048 + s0 + lc);
  *(bf16x8*)dst       = *(bf16x8*)tmp;
  *(bf16x8*)(dst + 8) = *(bf16x8*)(tmp + 8);
}

// ---------- causal flash attention ----------
// grid (qt=32, bh=32); 4 waves/block, 16 q-rows/wave, KV tile = 32
__global__ __launch_bounds__(256, 2)
void attn_fwd(const u16* __restrict__ QKV, const u16* __restrict__ Vt,
              u16* __restrict__ AO) {
  __shared__ u16 Ks[32 * 128];            // XOR-swizzled content (byte ^ ((row&7)<<4))
  __shared__ u16 Vs[128 * 32];            // Vt tile, [d][kv] row-major (64B rows)
  __shared__ u16 Ps[4][16][40];           // per-wave P roundtrip
  const int tid = threadIdx.x, lane = tid & 63, w = tid >> 6;
  const int g = lane >> 4, l16 = lane & 15;
  const int bh = blockIdx.y, b = bh >> 4, h = bh & 15;
  const int qt = blockIdx.x;
  const int q0 = qt * 64 + w * 16;

  bf16x8 qf[4];
  {
    const u16* qrow = QKV + ((size_t)(b * 2048 + q0 + l16) * 6144 + h * 128 + g * 8);
#pragma unroll
    for (int c = 0; c < 4; ++c) qf[c] = *(const bf16x8*)(qrow + c * 32);
  }
  f32x4 o[8] = {};
  float mrun[4] = {-INFINITY, -INFINITY, -INFINITY, -INFINITY};
  float lrun[4] = {0.f, 0.f, 0.f, 0.f};

  const int kv_end = qt * 64 + 64;
  for (int kv0 = 0; kv0 < kv_end; kv0 += 32) {
    __syncthreads();
#pragma unroll
    for (int i = 0; i < 2; ++i) {
      int idx = i * 256 + tid;
      {
        int row = idx >> 4;
        int colb = (idx & 15) * 16;
        int scolb = colb ^ ((row & 7) << 4);   // pre-swizzle the GLOBAL source
        gload_lds16((const char*)QKV +
                        ((size_t)(b * 2048 + kv0 + row) * 6144 + 2048 + h * 128) * 2 + scolb,
                    (char*)Ks + idx * 16);
      }
      {
        int d = idx >> 2, kvc = (idx & 3) * 8;
        gload_lds16(Vt + ((size_t)(bh * 128 + d) * 2048 + kv0 + kvc),
                    (char*)Vs + idx * 16);
      }
    }
    __syncthreads();

    f32x4 s[2];
#pragma unroll
    for (int kb = 0; kb < 2; ++kb) {
      f32x4 a = {};
      int row = kb * 16 + l16;
      int swz = (row & 7) << 4;
#pragma unroll
      for (int c = 0; c < 4; ++c) {
        bf16x8 kf = *(const bf16x8*)((const char*)Ks + row * 256 + ((c * 64 + g * 16) ^ swz));
        a = __builtin_amdgcn_mfma_f32_16x16x32_bf16(qf[c], kf, a, 0, 0, 0);
      }
      s[kb] = a * 0.08838834764831845f;   // 1/sqrt(128)
    }
    // causal mask: score col (key) = kv0+kb*16+l16, row (q) = q0+g*4+r
#pragma unroll
    for (int kb = 0; kb < 2; ++kb)
#pragma unroll
      for (int r = 0; r < 4; ++r)
        if (kv0 + kb * 16 + l16 > q0 + g * 4 + r) s[kb][r] = -INFINITY;

    float mnew[4], al[4], rs[4];
#pragma unroll
    for (int r = 0; r < 4; ++r) {
      float t = fmaxf(s[0][r], s[1][r]);
      t = fmaxf(t, __shfl_xor(t, 1));
      t = fmaxf(t, __shfl_xor(t, 2));
      t = fmaxf(t, __shfl_xor(t, 4));
      t = fmaxf(t, __shfl_xor(t, 8));
      mnew[r] = fmaxf(mrun[r], t);
      al[r] = __expf(mrun[r] - mnew[r]);  // first tile: exp(-inf - finite) = 0
      mrun[r] = mnew[r];
      rs[r] = 0.f;
    }
#pragma unroll
    for (int kb = 0; kb < 2; ++kb)
#pragma unroll
      for (int r = 0; r < 4; ++r) {
        float p = __expf(s[kb][r] - mnew[r]);
        rs[r] += p;
        Ps[w][g * 4 + r][kb * 16 + l16] = f2bf(p);
      }
#pragma unroll
    for (int r = 0; r < 4; ++r) {
      float t = rs[r];
      t += __shfl_xor(t, 1);
      t += __shfl_xor(t, 2);
      t += __shfl_xor(t, 4);
      t += __shfl_xor(t, 8);
      lrun[r] = lrun[r] * al[r] + t;
    }
#pragma unroll
    for (int db = 0; db < 8; ++db)
#pragma unroll
      for (int r = 0; r < 4; ++r) o[db][r] *= al[r];

    bf16x8 pa = *(const bf16x8*)&Ps[w][l16][g * 8];   // A-layout read of P
#pragma unroll
    for (int db = 0; db < 8; ++db) {
      bf16x8 vf = *(const bf16x8*)((const char*)Vs + (db * 16 + l16) * 64 + g * 16);
      o[db] = __builtin_amdgcn_mfma_f32_16x16x32_bf16(pa, vf, o[db], 0, 0, 0);
    }
  }

#pragma unroll
  for (int db = 0; db < 8; ++db)
#pragma unroll
    for (int r = 0; r < 4; ++r) {
      int q = q0 + g * 4 + r;
      AO[(size_t)(b * 2048 + q) * 2048 + h * 128 + db * 16 + l16] = f2bf(o[db][r] / lrun[r]);
    }
}

// ---------- launch ----------
extern "C" void kernel_launch(void* const* d_in, const int* in_sizes, int n_in,
                              void* d_out, int out_size, void* d_ws, size_t ws_size,
                              hipStream_t stream) {
  const float* x  = (const float*)d_in[0];
  const float* wq = (const float*)d_in[1];
  const float* wk = (const float*)d_in[2];
  const float* wv = (const float*)d_in[3];
  const float* wo = (const float*)d_in[4];
  float* out = (float*)d_out;

  char* ws = (char*)d_ws;
  u16* Xb   = (u16*)(ws);                         // 4096x2048        16 MB
  u16* Wqkv = (u16*)(ws + ((size_t)16 << 20));    // 6144x2048        24 MB
  u16* Wob  = (u16*)(ws + ((size_t)40 << 20));    // 2048x2048         8 MB
  u16* QKV  = (u16*)(ws + ((size_t)48 << 20));    // 4096x6144        48 MB
  u16* Vt   = (u16*)(ws + ((size_t)96 << 20));    // 2x16x128x2048    16 MB
  u16* AO   = (u16*)(ws + ((size_t)112 << 20));   // 4096x2048        16 MB

  auto cvt = [&](const float* s, u16* d, int n) {
    int blocks = (n / 8 + 255) / 256;
    if (blocks > 2048) blocks = 2048;
    cvt_f32_bf16<<<blocks, 256, 0, stream>>>(s, d, n);
  };
  cvt(x,  Xb,              2 * 2048 * 2048);
  cvt(wq, Wqkv,            2048 * 2048);
  cvt(wk, Wqkv + 4194304,  2048 * 2048);
  cvt(wv, Wqkv + 8388608,  2048 * 2048);
  cvt(wo, Wob,             2048 * 2048);

  gemm_bt<u16><<<dim3(48, 32), 256, 0, stream>>>(Xb, Wqkv, QKV, 4096, 6144, 2048);
  transpose_v<<<dim3(32, 64), 256, 0, stream>>>(QKV, Vt);
  attn_fwd<<<dim3(32, 32), 256, 0, stream>>>(QKV, Vt, AO);
  gemm_bt<float><<<dim3(16, 32), 256, 0, stream>>>(AO, Wob, out, 4096, 2048, 2048);
}

// Round 2
// 411.747 us; speedup vs baseline: 1.2723x; 1.2723x over previous
//
#include <hip/hip_runtime.h>
#include <hip/hip_bf16.h>
#include <math.h>

typedef unsigned short u16;
typedef __attribute__((ext_vector_type(8))) short bf16x8;   // 8 bf16 = 4 VGPRs
typedef __attribute__((ext_vector_type(4))) float f32x4;

// ---------- helpers ----------
__device__ static inline u16 f2bf(float f) {
  unsigned u = __float_as_uint(f);
  u += 0x7fff + ((u >> 16) & 1);          // RNE; inputs are finite normals
  return (u16)(u >> 16);
}

__device__ static inline void gload_lds16(const void* g, void* l) {
  __builtin_amdgcn_global_load_lds(
      (const __attribute__((address_space(1))) unsigned int*)g,
      (__attribute__((address_space(3))) unsigned int*)l, 16, 0, 0);
}

__device__ static inline void store_out(u16* p, float v)   { *p = f2bf(v); }
__device__ static inline void store_out(float* p, float v) { *p = v; }

// ---------- fp32 -> bf16 convert ----------
__global__ void cvt_f32_bf16(const float* __restrict__ src, u16* __restrict__ dst, int n) {
  int stride = gridDim.x * blockDim.x;
  for (int i = blockIdx.x * blockDim.x + threadIdx.x; i * 8 < n; i += stride) {
    const float4* s4 = (const float4*)(src + (size_t)i * 8);
    float4 a = s4[0], b = s4[1];
    u16 t[8] = { f2bf(a.x), f2bf(a.y), f2bf(a.z), f2bf(a.w),
                 f2bf(b.x), f2bf(b.y), f2bf(b.z), f2bf(b.w) };
    *(bf16x8*)(dst + (size_t)i * 8) = *(bf16x8*)t;
  }
}

// ---------- GEMM: C[M][N] = A[M][K] * B[N][K]^T  (m97 structure) ----------
template <typename OutT>
__global__ __launch_bounds__(256, 2)
void gemm_bt(const u16* __restrict__ A, const u16* __restrict__ Bm,
             OutT* __restrict__ C, int M, int N, int K) {
  __shared__ u16 As[128 * 32];
  __shared__ u16 Bs[128 * 32];
  const int tid = threadIdx.x;
  const int lane = tid & 63;
  const int w = tid >> 6, wr = w >> 1, wc = w & 1;
  const int g = lane >> 4, l16 = lane & 15;
  const int row0 = blockIdx.y * 128, col0 = blockIdx.x * 128;
  f32x4 acc[4][4] = {};

  for (int k0 = 0; k0 < K; k0 += 32) {
    __syncthreads();
#pragma unroll
    for (int i = 0; i < 2; ++i) {
      int idx = i * 256 + tid;            // 512 x 16B chunks per operand
      int r = idx >> 2, c = (idx & 3) * 8;
      gload_lds16(A  + (size_t)(row0 + r) * K + k0 + c, As + idx * 8);
      gload_lds16(Bm + (size_t)(col0 + r) * K + k0 + c, Bs + idx * 8);
    }
    __syncthreads();                      // drains vmcnt(0) before barrier
    bf16x8 af[4], bfr[4];
#pragma unroll
    for (int m2 = 0; m2 < 4; ++m2)
      af[m2] = *(const bf16x8*)(As + (wr * 64 + m2 * 16 + l16) * 32 + g * 8);
#pragma unroll
    for (int n2 = 0; n2 < 4; ++n2)
      bfr[n2] = *(const bf16x8*)(Bs + (wc * 64 + n2 * 16 + l16) * 32 + g * 8);
#pragma unroll
    for (int m2 = 0; m2 < 4; ++m2)
#pragma unroll
      for (int n2 = 0; n2 < 4; ++n2)
        acc[m2][n2] = __builtin_amdgcn_mfma_f32_16x16x32_bf16(af[m2], bfr[n2], acc[m2][n2], 0, 0, 0);
  }

#pragma unroll
  for (int m2 = 0; m2 < 4; ++m2)
#pragma unroll
    for (int n2 = 0; n2 < 4; ++n2) {
      int col = col0 + wc * 64 + n2 * 16 + l16;
#pragma unroll
      for (int r = 0; r < 4; ++r) {
        int row = row0 + wr * 64 + m2 * 16 + g * 4 + r;
        store_out(C + (size_t)row * N + col, acc[m2][n2][r]);
      }
    }
}

// ---------- V transpose: QKV V-part [b,s,h*128+d] -> Vt [b,h,d,s] ----------
__global__ __launch_bounds__(256)
void transpose_v(const u16* __restrict__ QKV, u16* __restrict__ Vt) {
  __shared__ u16 t[64][72];
  const int tid = threadIdx.x;
  const int b = blockIdx.y >> 5;
  const int s0 = (blockIdx.y & 31) * 64;
  const int hd0 = blockIdx.x * 64;
  const int lr = tid >> 2, lc = (tid & 3) * 16;
  const u16* src = QKV + ((size_t)(b * 2048 + s0 + lr) * 6144 + 4096 + hd0 + lc);
  *(bf16x8*)&t[lr][lc]     = *(const bf16x8*)src;
  *(bf16x8*)&t[lr][lc + 8] = *(const bf16x8*)(src + 8);
  __syncthreads();
  u16 tmp[16];
#pragma unroll
  for (int j = 0; j < 16; ++j) tmp[j] = t[lc + j][lr];
  u16* dst = Vt + ((size_t)(b * 2048 + hd0 + lr) * 2048 + s0 + lc);
  *(bf16x8*)dst       = *(bf16x8*)tmp;
  *(bf16x8*)(dst + 8) = *(bf16x8*)(tmp + 8);
}

// ---------- causal flash attention (v2) ----------
// Folded causal schedule: block (fold, bh) processes q-tiles qt = fold and
// 31-fold (64 q-rows each) -> every block does exactly 33 KV-64 tiles.
// 4 waves/block, 16 q-rows/wave, KVBLK = 64.
// LDS: Ks[64][128] (swz), Vs[128][64] (swz), Ps[4][16][64] (swz) = 40 KB.
__global__ __launch_bounds__(256, 2)
void attn_fwd(const u16* __restrict__ QKV, const u16* __restrict__ Vt,
              u16* __restrict__ AO) {
  __shared__ u16 Ks[64 * 128];
  __shared__ u16 Vs[128 * 64];
  __shared__ u16 Ps[4][16 * 64];
  const int tid = threadIdx.x, lane = tid & 63, w = tid >> 6;
  const int g = lane >> 4, l16 = lane & 15;
  const int bh = blockIdx.y, b = bh >> 4, h = bh & 15;
  const int fold = blockIdx.x;

  for (int phase = 0; phase < 2; ++phase) {
    const int qt = phase == 0 ? fold : 31 - fold;
    const int q0 = qt * 64 + w * 16;

    bf16x8 qf[4];
    {
      const u16* qrow = QKV + ((size_t)(b * 2048 + q0 + l16) * 6144 + h * 128 + g * 8);
#pragma unroll
      for (int c = 0; c < 4; ++c) qf[c] = *(const bf16x8*)(qrow + c * 32);
    }
    f32x4 o[8] = {};
    float mrun[4] = {-INFINITY, -INFINITY, -INFINITY, -INFINITY};
    float lrun[4] = {0.f, 0.f, 0.f, 0.f};

    const int kv_last = qt * 64;          // diagonal tile
    for (int kv0 = 0; kv0 <= kv_last; kv0 += 64) {
      __syncthreads();
#pragma unroll
      for (int i = 0; i < 4; ++i) {
        int idx = i * 256 + tid;          // 1024 x 16B per operand
        {
          int row = idx >> 4;
          int scolb = ((idx & 15) * 16) ^ ((row & 7) << 4);
          gload_lds16((const char*)QKV +
                          ((size_t)(b * 2048 + kv0 + row) * 6144 + 2048 + h * 128) * 2 + scolb,
                      (char*)Ks + idx * 16);
        }
        {
          int d = idx >> 3;
          int vcolb = ((idx & 7) * 16) ^ ((d & 7) << 4);
          gload_lds16((const char*)Vt + ((size_t)(bh * 128 + d) * 2048 + kv0) * 2 + vcolb,
                      (char*)Vs + idx * 16);
        }
      }
      __syncthreads();

      // QK^T: S[q=g*4+r][k=kb*16+l16]
      f32x4 s[4];
#pragma unroll
      for (int kb = 0; kb < 4; ++kb) {
        f32x4 a = {};
        int row = kb * 16 + l16;
        int swz = (row & 7) << 4;
#pragma unroll
        for (int c = 0; c < 4; ++c) {
          bf16x8 kf = *(const bf16x8*)((const char*)Ks + row * 256 + ((c * 64 + g * 16) ^ swz));
          a = __builtin_amdgcn_mfma_f32_16x16x32_bf16(qf[c], kf, a, 0, 0, 0);
        }
        s[kb] = a * 0.08838834764831845f; // 1/sqrt(128)
      }
      if (kv0 == kv_last) {               // diagonal tile only
#pragma unroll
        for (int kb = 0; kb < 4; ++kb)
#pragma unroll
          for (int r = 0; r < 4; ++r)
            if (kv0 + kb * 16 + l16 > q0 + g * 4 + r) s[kb][r] = -INFINITY;
      }

      float mnew[4], al[4], rs[4];
#pragma unroll
      for (int r = 0; r < 4; ++r) {
        float t = fmaxf(fmaxf(s[0][r], s[1][r]), fmaxf(s[2][r], s[3][r]));
        t = fmaxf(t, __shfl_xor(t, 1));
        t = fmaxf(t, __shfl_xor(t, 2));
        t = fmaxf(t, __shfl_xor(t, 4));
        t = fmaxf(t, __shfl_xor(t, 8));
        mnew[r] = fmaxf(mrun[r], t);
        al[r] = __expf(mrun[r] - mnew[r]);
        mrun[r] = mnew[r];
        rs[r] = 0.f;
      }
      {
        int prow = g * 4;                 // write P (swizzled rows of 128B)
#pragma unroll
        for (int kb = 0; kb < 4; ++kb)
#pragma unroll
          for (int r = 0; r < 4; ++r) {
            float p = __expf(s[kb][r] - mnew[r]);
            rs[r] += p;
            int row = prow + r;
            int byteoff = (kb * 32 + l16 * 2) ^ ((row & 7) << 4);
            *(u16*)((char*)Ps[w] + row * 128 + byteoff) = f2bf(p);
          }
      }
#pragma unroll
      for (int r = 0; r < 4; ++r) {
        float t = rs[r];
        t += __shfl_xor(t, 1);
        t += __shfl_xor(t, 2);
        t += __shfl_xor(t, 4);
        t += __shfl_xor(t, 8);
        lrun[r] = lrun[r] * al[r] + t;
      }
#pragma unroll
      for (int db = 0; db < 8; ++db)
#pragma unroll
        for (int r = 0; r < 4; ++r) o[db][r] *= al[r];

      // PV: A = P rows q=l16, B = V^T rows d=db*16+l16
      bf16x8 pa[2];
      {
        int swz = (l16 & 7) << 4;
#pragma unroll
        for (int ks = 0; ks < 2; ++ks)
          pa[ks] = *(const bf16x8*)((const char*)Ps[w] + l16 * 128 + ((ks * 64 + g * 16) ^ swz));
      }
#pragma unroll
      for (int db = 0; db < 8; ++db) {
        int row = db * 16 + l16;
        int swz = (row & 7) << 4;
#pragma unroll
        for (int ks = 0; ks < 2; ++ks) {
          bf16x8 vf = *(const bf16x8*)((const char*)Vs + row * 128 + ((ks * 64 + g * 16) ^ swz));
          o[db] = __builtin_amdgcn_mfma_f32_16x16x32_bf16(pa[ks], vf, o[db], 0, 0, 0);
        }
      }
    }

#pragma unroll
    for (int r = 0; r < 4; ++r) {
      float rl = 1.0f / lrun[r];
      int q = q0 + g * 4 + r;
#pragma unroll
      for (int db = 0; db < 8; ++db)
        AO[(size_t)(b * 2048 + q) * 2048 + h * 128 + db * 16 + l16] = f2bf(o[db][r] * rl);
    }
  }
}

// ---------- launch ----------
extern "C" void kernel_launch(void* const* d_in, const int* in_sizes, int n_in,
                              void* d_out, int out_size, void* d_ws, size_t ws_size,
                              hipStream_t stream) {
  const float* x  = (const float*)d_in[0];
  const float* wq = (const float*)d_in[1];
  const float* wk = (const float*)d_in[2];
  const float* wv = (const float*)d_in[3];
  const float* wo = (const float*)d_in[4];
  float* out = (float*)d_out;

  char* ws = (char*)d_ws;
  u16* Xb   = (u16*)(ws);                         // 4096x2048        16 MB
  u16* Wqkv = (u16*)(ws + ((size_t)16 << 20));    // 6144x2048        24 MB
  u16* Wob  = (u16*)(ws + ((size_t)40 << 20));    // 2048x2048         8 MB
  u16* QKV  = (u16*)(ws + ((size_t)48 << 20));    // 4096x6144        48 MB
  u16* Vt   = (u16*)(ws + ((size_t)96 << 20));    // 2x16x128x2048    16 MB
  u16* AO   = (u16*)(ws + ((size_t)112 << 20));   // 4096x2048        16 MB

  auto cvt = [&](const float* s, u16* d, int n) {
    int blocks = (n / 8 + 255) / 256;
    if (blocks > 2048) blocks = 2048;
    cvt_f32_bf16<<<blocks, 256, 0, stream>>>(s, d, n);
  };
  cvt(x,  Xb,              2 * 2048 * 2048);
  cvt(wq, Wqkv,            2048 * 2048);
  cvt(wk, Wqkv + 4194304,  2048 * 2048);
  cvt(wv, Wqkv + 8388608,  2048 * 2048);
  cvt(wo, Wob,             2048 * 2048);

  gemm_bt<u16><<<dim3(48, 32), 256, 0, stream>>>(Xb, Wqkv, QKV, 4096, 6144, 2048);
  transpose_v<<<dim3(32, 64), 256, 0, stream>>>(QKV, Vt);
  attn_fwd<<<dim3(16, 32), 256, 0, stream>>>(QKV, Vt, AO);
  gemm_bt<float><<<dim3(16, 32), 256, 0, stream>>>(AO, Wob, out, 4096, 2048, 2048);
}